// Round 5
// baseline (59.764 us; speedup 1.0000x reference)
//
#include <hip/hip_runtime.h>
#include <stdint.h>

static constexpr int B = 8, C = 21, H = 512, W = 512;
static constexpr int HW = H * W;          // 262144
static constexpr int N = B * HW;          // 2097152 pixels
static constexpr int CHUNKS = 32;         // 168*32 = 5376 blocks = EXACTLY 21/CU (no tail)
static constexpr int PPC = HW / CHUNKS;   // 8192 pixels per workgroup (< 2^16: u16-pack safe)
static constexpr int ITER = PPC / 4 / 256;// 8 x (float4 + int4) loads per thread
static constexpr int NPART = B * CHUNKS;  // 256 partial hists per class
static constexpr int NBMAX = 512;         // quantization bound 0.5/nb = 9.8e-4 << 1.77e-2

// ---------------------------------------------------------------------------
// Pass 1: LDS-privatized per-(class,bucket) histogram. Packed u32: count in
// low 16, gt-count in high 16 (chunk = 8192 pixels -> no overflow). Labels
// are read directly as int4 (the 21x per-class re-read is L3-resident; a
// separate u8-compression pass measured SLOWER in round 3). Flush = plain
// coalesced stores to a per-workgroup slab: zero global atomics.
// Grid = 5376 blocks = exactly 21 per CU -> no dispatch-imbalance tail
// (round-4's 1344 = 5.25/CU cost ~14% idle).
// ---------------------------------------------------------------------------
__global__ __launch_bounds__(256) void hist_kernel(const float4* __restrict__ pred,
                                                   const int4* __restrict__ lab4,
                                                   unsigned* __restrict__ part,
                                                   int nb, float nbf) {
    int chunk = blockIdx.x;               // 0..CHUNKS-1
    int bc = blockIdx.y;                  // b*C + c
    int b = bc / C, c = bc % C;
    int tid = threadIdx.x;

    __shared__ unsigned hcnt[NBMAX];
    for (int j = tid; j < nb; j += 256) hcnt[j] = 0;
    __syncthreads();

    const float4* pp = pred + ((size_t)bc * HW + (size_t)chunk * PPC) / 4;
    const int4* lp = lab4 + ((size_t)b * HW + (size_t)chunk * PPC) / 4;
#pragma unroll
    for (int i = 0; i < ITER; ++i) {
        int idx = i * 256 + tid;
        float4 p = pp[idx];
        int4 lv = lp[idx];
        float pe[4] = {p.x, p.y, p.z, p.w};
        int le[4] = {lv.x, lv.y, lv.z, lv.w};
#pragma unroll
        for (int j = 0; j < 4; ++j) {
            unsigned ismatch = (le[j] == c) ? 1u : 0u;
            float e = fabsf((float)ismatch - pe[j]);
            int q = (int)(e * nbf);
            q = q > nb - 1 ? nb - 1 : (q < 0 ? 0 : q);
            atomicAdd(&hcnt[q], 1u | (ismatch << 16));
        }
    }
    __syncthreads();

    unsigned* dst = part + ((size_t)c * NPART + (size_t)(b * CHUNKS + chunk)) * nb;
    for (int j = tid; j < nb; j += 256) dst[j] = hcnt[j];   // coalesced
}

// ---------------------------------------------------------------------------
// Pass 2: fold the 256 partials per class into one u64 hist (n lo32, g hi32).
// 64-thread blocks -> 168 blocks spread across CUs (256-thread blocks would
// give only 42). Also zeroes the scan's done-counter.
// ---------------------------------------------------------------------------
__global__ __launch_bounds__(64) void reduce_kernel(const unsigned* __restrict__ part,
                                                    unsigned long long* __restrict__ hist,
                                                    int nb,
                                                    unsigned* __restrict__ done) {
    if (blockIdx.x == 0 && threadIdx.x == 0) *done = 0u;
    int idx = blockIdx.x * 64 + threadIdx.x;   // c*nb + q
    if (idx >= C * nb) return;
    int c = idx / nb, q = idx - c * nb;
    const unsigned* basep = part + (size_t)c * NPART * nb + q;
    unsigned n = 0, g = 0;
#pragma unroll 8
    for (int p = 0; p < NPART; ++p) {
        unsigned v = basep[(size_t)p * nb];
        n += v & 0xffffu;
        g += v >> 16;
    }
    hist[idx] = (unsigned long long)n | ((unsigned long long)g << 32);
}

// ---------------------------------------------------------------------------
// Pass 3: per class, scan buckets in DESCENDING error order. Tied-bucket
// contribution telescopes to e_rep * (J(k+n,cg+g) - J(k,cg)),
// J(k,cg) = 1 - (G-cg)/(G+k-cg). Last block to finish computes the mean over
// present classes (device-scope atomic + fences: order-independent sum).
// ---------------------------------------------------------------------------
__global__ __launch_bounds__(256) void scan_kernel(const unsigned long long* __restrict__ hist,
                                                   int nb,
                                                   double* __restrict__ loss_out,
                                                   unsigned long long* __restrict__ g_out,
                                                   unsigned* __restrict__ done,
                                                   float* __restrict__ out) {
    int c = blockIdx.x;
    int tid = threadIdx.x;
    int per = nb / 256;

    __shared__ unsigned cn[NBMAX], cgx[NBMAX];
    for (int j = tid; j < nb; j += 256) {
        unsigned long long v = hist[(size_t)c * nb + j];
        cn[j] = (unsigned)(v & 0xffffffffULL);
        cgx[j] = (unsigned)(v >> 32);
    }
    __syncthreads();

    unsigned long long nsum = 0, gsum = 0;
    for (int j = 0; j < per; ++j) {
        int q = nb - 1 - (tid * per + j);
        nsum += cn[q]; gsum += cgx[q];
    }
    __shared__ unsigned long long sn[256], sg[256], exn[257], exg[257];
    sn[tid] = nsum; sg[tid] = gsum;
    __syncthreads();
    if (tid == 0) {
        unsigned long long an = 0, ag = 0;
        for (int i = 0; i < 256; ++i) { exn[i] = an; exg[i] = ag; an += sn[i]; ag += sg[i]; }
        exn[256] = an; exg[256] = ag;
    }
    __syncthreads();

    unsigned long long G = exg[256];
    double acc = 0.0;
    if (G > 0) {
        double Gd = (double)G;
        double k  = (double)exn[tid];
        double cg = (double)exg[tid];
        double jprev = 1.0 - (Gd - cg) / (Gd + k - cg);
        double inv_nb = 1.0 / (double)nb;
        for (int j = 0; j < per; ++j) {
            int q = nb - 1 - (tid * per + j);
            unsigned n = cn[q];
            if (n) {
                k += (double)n; cg += (double)cgx[q];
                double jnew = 1.0 - (Gd - cg) / (Gd + k - cg);
                acc += (((double)q + 0.5) * inv_nb) * (jnew - jprev);
                jprev = jnew;
            }
        }
    }
    __shared__ double red[256];
    red[tid] = acc;
    __syncthreads();
    for (int s = 128; s > 0; s >>= 1) {
        if (tid < s) red[tid] += red[tid + s];
        __syncthreads();
    }
    if (tid == 0) {
        loss_out[c] = red[0];
        g_out[c] = G;
        __threadfence();                       // publish before signaling
        unsigned old = atomicAdd(done, 1u);    // device-scope
        if (old == C - 1) {                    // last block finalizes
            __threadfence();                   // acquire others' writes
            double s = 0.0; int np = 0;
            for (int i = 0; i < C; ++i)
                if (g_out[i] > 0) { s += loss_out[i]; ++np; }
            out[0] = (float)(s / (double)(np > 0 ? np : 1));
        }
    }
}

extern "C" void kernel_launch(void* const* d_in, const int* in_sizes, int n_in,
                              void* d_out, int out_size, void* d_ws, size_t ws_size,
                              hipStream_t stream) {
    const float* pred = (const float*)d_in[0];
    const int* tgt = (const int*)d_in[1];   // int64 narrowed to int32 by harness (validated)
    float* out = (float*)d_out;

    int nb = NBMAX;
    while (nb > 128) {
        size_t need = (size_t)C * NPART * nb * 4 + (size_t)C * nb * 8 + 4096;
        if (need <= ws_size) break;
        nb >>= 1;
    }

    char* ws = (char*)d_ws;
    unsigned* part = (unsigned*)ws;                                  // C*NPART*nb*4
    unsigned long long* hist =
        (unsigned long long*)(ws + (size_t)C * NPART * nb * 4);      // C*nb*8
    double* loss = (double*)((char*)hist + (size_t)C * nb * 8);      // C*8
    unsigned long long* g = (unsigned long long*)(loss + C);         // C*8
    unsigned* done = (unsigned*)(g + C);                             // 4

    hist_kernel<<<dim3(CHUNKS, B * C), dim3(256), 0, stream>>>(
        (const float4*)pred, (const int4*)tgt, part, nb, (float)nb);
    reduce_kernel<<<dim3((C * nb + 63) / 64), dim3(64), 0, stream>>>(part, hist, nb, done);
    scan_kernel<<<dim3(C), dim3(256), 0, stream>>>(hist, nb, loss, g, done, out);
}

// Round 6
// 59.129 us; speedup vs baseline: 1.0107x; 1.0107x over previous
//
#include <hip/hip_runtime.h>
#include <stdint.h>

static constexpr int B = 8, C = 21, H = 512, W = 512;
static constexpr int HW = H * W;            // 262144
static constexpr int N = B * HW;            // 2097152 pixels
static constexpr int NB = 256;              // buckets; quantization bound 0.5/NB = 1.95e-3 << 1.77e-2
static constexpr int TPB = 1024;            // threads per hist block
static constexpr int PPB = 4096;            // pixels per hist block (<2^16: u16-pack safe)
static constexpr int BLOCKS = N / PPB;      // 512 = exactly 2 blocks/CU
static constexpr int BPI = HW / PPB;        // 64 blocks per image

// ---------------------------------------------------------------------------
// Pass 1 (transposed decomposition): each block owns 4096 PIXELS and loops
// over all 21 class planes. Labels are read ONCE into registers (8 MB total,
// vs round-4's 21x168 MB L3 re-broadcast); pred is read exactly once overall.
// 21 per-class LDS histograms (21 KB); packed u32 (count lo16, gt hi16).
// 2-deep prefetch pipelines the next class plane's float4 under the current
// class's VALU+LDS-atomic work. Flush = plain coalesced stores, no global
// atomics.
// ---------------------------------------------------------------------------
__global__ __launch_bounds__(TPB) void hist_kernel(const float4* __restrict__ pred,
                                                   const int4* __restrict__ lab4,
                                                   unsigned* __restrict__ part) {
    int blk = blockIdx.x, tid = threadIdx.x;
    int b = blk / BPI, off = (blk % BPI) * PPB;

    __shared__ unsigned hist[C][NB];
    unsigned* hs = &hist[0][0];
    for (int j = tid; j < C * NB; j += TPB) hs[j] = 0;
    __syncthreads();

    int4 lv = lab4[((size_t)b * HW + off) / 4 + tid];
    int le[4] = {lv.x, lv.y, lv.z, lv.w};

    const float4* pp = pred + ((size_t)b * C * HW + off) / 4 + tid;
    float4 p0 = pp[0];                        // class 0
    float4 p1 = pp[HW / 4];                   // class 1
    for (int c = 0; c < C; ++c) {
        float4 pn = p1;
        if (c + 2 < C) pn = pp[(size_t)(c + 2) * (HW / 4)];
        float pe[4] = {p0.x, p0.y, p0.z, p0.w};
#pragma unroll
        for (int j = 0; j < 4; ++j) {
            int qp = (int)(pe[j] * (float)NB);
            qp = qp > NB - 1 ? NB - 1 : (qp < 0 ? 0 : qp);
            bool m = (le[j] == c);
            int q = m ? NB - 1 - qp : qp;     // e = m ? 1-p : p, bucketized
            atomicAdd(&hist[c][q], m ? 0x10001u : 1u);
        }
        p0 = p1; p1 = pn;
    }
    __syncthreads();

    // part[(c*BLOCKS + blk)*NB + q]
    for (int j = tid; j < C * NB; j += TPB) {
        int c = j / NB, q = j - c * NB;
        part[((size_t)c * BLOCKS + blk) * NB + q] = hs[j];
    }
}

// ---------------------------------------------------------------------------
// Pass 2: one block per class. Each thread owns ONE bucket (descending q by
// thread id), folds the 512 per-block partials (slab is L2/L3-resident),
// then the Lovasz scan: exclusive prefix over threads + tied-bucket telescope
// e_rep * (J(k+n,cg+g) - J(k,cg)), J(k,cg) = 1 - (G-cg)/(G+k-cg).
// ---------------------------------------------------------------------------
__global__ __launch_bounds__(NB) void scanred_kernel(const unsigned* __restrict__ part,
                                                     double* __restrict__ loss_out,
                                                     unsigned long long* __restrict__ g_out) {
    int c = blockIdx.x;
    int tid = threadIdx.x;
    int q = NB - 1 - tid;                     // descending error order

    const unsigned* basep = part + (size_t)c * BLOCKS * NB + q;
    unsigned n = 0, g = 0;
#pragma unroll 8
    for (int p = 0; p < BLOCKS; ++p) {
        unsigned v = basep[(size_t)p * NB];
        n += v & 0xffffu;
        g += v >> 16;
    }

    __shared__ unsigned sn[NB], sg[NB];
    __shared__ unsigned exn[NB + 1], exg[NB + 1];
    sn[tid] = n; sg[tid] = g;
    __syncthreads();
    if (tid == 0) {
        unsigned an = 0, ag = 0;
        for (int i = 0; i < NB; ++i) { exn[i] = an; exg[i] = ag; an += sn[i]; ag += sg[i]; }
        exn[NB] = an; exg[NB] = ag;
    }
    __syncthreads();

    unsigned G = exg[NB];
    double acc = 0.0;
    if (G > 0 && n > 0) {
        double Gd = (double)G;
        double k = (double)exn[tid], cg = (double)exg[tid];
        double jprev = 1.0 - (Gd - cg) / (Gd + k - cg);
        double k2 = k + (double)n, cg2 = cg + (double)g;
        double jnew = 1.0 - (Gd - cg2) / (Gd + k2 - cg2);
        acc = (((double)q + 0.5) / (double)NB) * (jnew - jprev);
    }

    __shared__ double red[NB];
    red[tid] = acc;
    __syncthreads();
    for (int s = NB / 2; s > 0; s >>= 1) {
        if (tid < s) red[tid] += red[tid + s];
        __syncthreads();
    }
    if (tid == 0) { loss_out[c] = red[0]; g_out[c] = G; }
}

// ---------------------------------------------------------------------------
// Pass 3: mean over present classes.
// ---------------------------------------------------------------------------
__global__ void finalize_kernel(const double* __restrict__ loss,
                                const unsigned long long* __restrict__ g,
                                float* __restrict__ out) {
    if (blockIdx.x == 0 && threadIdx.x == 0) {
        double s = 0.0; int np = 0;
        for (int c = 0; c < C; ++c) if (g[c] > 0) { s += loss[c]; ++np; }
        out[0] = (float)(s / (double)(np > 0 ? np : 1));
    }
}

extern "C" void kernel_launch(void* const* d_in, const int* in_sizes, int n_in,
                              void* d_out, int out_size, void* d_ws, size_t ws_size,
                              hipStream_t stream) {
    const float* pred = (const float*)d_in[0];
    const int* tgt = (const int*)d_in[1];   // int64 narrowed to int32 by harness (validated)
    float* out = (float*)d_out;

    char* ws = (char*)d_ws;
    unsigned* part = (unsigned*)ws;                                  // C*BLOCKS*NB*4 = 11 MB
    double* loss = (double*)(ws + (size_t)C * BLOCKS * NB * 4);      // C*8
    unsigned long long* g = (unsigned long long*)(loss + C);         // C*8

    hist_kernel<<<dim3(BLOCKS), dim3(TPB), 0, stream>>>(
        (const float4*)pred, (const int4*)tgt, part);
    scanred_kernel<<<dim3(C), dim3(NB), 0, stream>>>(part, loss, g);
    finalize_kernel<<<1, 64, 0, stream>>>(loss, g, out);
}

// Round 12
// 46.293 us; speedup vs baseline: 1.2910x; 1.2773x over previous
//
#include <hip/hip_runtime.h>
#include <stdint.h>

static constexpr int B = 8, C = 21, H = 512, W = 512;
static constexpr int HW = H * W;            // 262144
static constexpr int N = B * HW;            // 2097152 pixels
static constexpr int CHUNKS = 8;            // round-4 geometry: best measured (51.6us)
static constexpr int PPC = HW / CHUNKS;     // 32768 pixels per hist block (u16-pack safe)
static constexpr int ITER = PPC / 4 / 256;  // 32 float4 iters per thread
static constexpr int NPART = B * CHUNKS;    // 64 partials per class
static constexpr int NB = 1024;             // quantization bound 0.5/NB = 4.9e-4 << 1.77e-2

// ---------------------------------------------------------------------------
// Pass 1: LDS-privatized per-(class,bucket) histogram. EXACT round-4 body
// (validated passing, 51.6us). 1344 blocks x 256 thr; packed u32 (count lo16,
// gt hi16); flush = plain coalesced stores; zero global atomics.
// ---------------------------------------------------------------------------
__global__ __launch_bounds__(256) void hist_kernel(const float4* __restrict__ pred,
                                                   const int4* __restrict__ lab4,
                                                   unsigned* __restrict__ part,
                                                   int nb, float nbf) {
    int chunk = blockIdx.x;               // 0..CHUNKS-1
    int bc = blockIdx.y;                  // b*C + c
    int b = bc / C, c = bc % C;
    int tid = threadIdx.x;

    __shared__ unsigned hcnt[NB];
    for (int j = tid; j < nb; j += 256) hcnt[j] = 0;
    __syncthreads();

    const float4* pp = pred + ((size_t)bc * HW + (size_t)chunk * PPC) / 4;
    const int4* lp = lab4 + ((size_t)b * HW + (size_t)chunk * PPC) / 4;
#pragma unroll 4
    for (int i = 0; i < ITER; ++i) {
        int idx = i * 256 + tid;
        float4 p = pp[idx];
        int4 lv = lp[idx];
        float pe[4] = {p.x, p.y, p.z, p.w};
        int le[4] = {lv.x, lv.y, lv.z, lv.w};
#pragma unroll
        for (int j = 0; j < 4; ++j) {
            unsigned ismatch = (le[j] == c) ? 1u : 0u;
            float e = fabsf((float)ismatch - pe[j]);
            int q = (int)(e * nbf);
            q = q > nb - 1 ? nb - 1 : (q < 0 ? 0 : q);
            atomicAdd(&hcnt[q], 1u | (ismatch << 16));
        }
    }
    __syncthreads();

    unsigned* dst = part + ((size_t)c * NPART + (size_t)(b * CHUNKS + chunk)) * NB;
    for (int j = tid; j < nb; j += 256) dst[j] = hcnt[j];   // coalesced
}

// ---------------------------------------------------------------------------
// Pass 2: one block per class, 1024 threads = one thread per bucket
// (q = NB-1-tid: tid order == descending error). Fold: each thread reads its
// bucket's 64 partials (wide, wave-coalesced, slab L2/L3-resident).
// Prefix: VALIDATED two-level form only (Hillis-Steele is the by-elimination
// culprit of rounds 8/9/10's identical deterministic failures):
//   group-of-4 sums -> serial thread-0 exclusive prefix over 256 groups
//   (round-4/5/6 pattern) -> <=3-term intra-group completion per thread.
// Telescope per thread (round-6 validated): e_rep*(J(k2,cg2)-J(k1,cg1)),
// J(k,cg) = 1 - (G-cg)/(G+k-cg).
// ---------------------------------------------------------------------------
__global__ __launch_bounds__(1024) void class_kernel(const unsigned* __restrict__ part,
                                                     double* __restrict__ loss_out,
                                                     unsigned long long* __restrict__ g_out) {
    int c = blockIdx.x;
    int tid = threadIdx.x;
    int q = NB - 1 - tid;

    const unsigned* basep = part + (size_t)c * NPART * NB + q;
    unsigned n = 0, g = 0;
#pragma unroll 8
    for (int p = 0; p < NPART; ++p) {
        unsigned v = basep[(size_t)p * NB];
        n += v & 0xffffu;
        g += v >> 16;
    }

    __shared__ unsigned sn[NB], sg[NB];
    sn[tid] = n; sg[tid] = g;
    __syncthreads();

    // level 1: group-of-4 sums (threads 0..255)
    __shared__ unsigned gn[256], gg[256];
    if (tid < 256) {
        unsigned a = 0, b2 = 0;
#pragma unroll
        for (int i = 0; i < 4; ++i) { a += sn[4 * tid + i]; b2 += sg[4 * tid + i]; }
        gn[tid] = a; gg[tid] = b2;
    }
    __syncthreads();

    // level 2: serial exclusive prefix over 256 groups (validated r4/5/6)
    __shared__ unsigned exn[257], exg[257];
    if (tid == 0) {
        unsigned an = 0, ag = 0;
        for (int i = 0; i < 256; ++i) { exn[i] = an; exg[i] = ag; an += gn[i]; ag += gg[i]; }
        exn[256] = an; exg[256] = ag;
    }
    __syncthreads();

    unsigned G = exg[256];

    // per-thread exclusive prefix: group base + <=3 intra-group predecessors
    unsigned k1u = exn[tid >> 2], cg1u = exg[tid >> 2];
    for (int i = (tid & ~3); i < tid; ++i) { k1u += sn[i]; cg1u += sg[i]; }

    double acc = 0.0;
    if (G > 0 && n > 0) {
        double Gd = (double)G;
        double k1 = (double)k1u, cg1 = (double)cg1u;
        double k2 = k1 + (double)n, cg2 = cg1 + (double)g;
        double jprev = 1.0 - (Gd - cg1) / (Gd + k1 - cg1);
        double jnew  = 1.0 - (Gd - cg2) / (Gd + k2 - cg2);
        acc = (((double)q + 0.5) / (double)NB) * (jnew - jprev);
    }

    __shared__ double red[NB];
    red[tid] = acc;
    __syncthreads();
    for (int s = NB / 2; s > 0; s >>= 1) {
        if (tid < s) red[tid] += red[tid + s];
        __syncthreads();
    }
    if (tid == 0) { loss_out[c] = red[0]; g_out[c] = G; }
}

// ---------------------------------------------------------------------------
// Pass 3: mean over present classes (separate kernel — validated r5/6).
// ---------------------------------------------------------------------------
__global__ void finalize_kernel(const double* __restrict__ loss,
                                const unsigned long long* __restrict__ g,
                                float* __restrict__ out) {
    if (blockIdx.x == 0 && threadIdx.x == 0) {
        double s = 0.0; int np = 0;
        for (int c = 0; c < C; ++c) if (g[c] > 0) { s += loss[c]; ++np; }
        out[0] = (float)(s / (double)(np > 0 ? np : 1));
    }
}

extern "C" void kernel_launch(void* const* d_in, const int* in_sizes, int n_in,
                              void* d_out, int out_size, void* d_ws, size_t ws_size,
                              hipStream_t stream) {
    const float* pred = (const float*)d_in[0];
    const int* tgt = (const int*)d_in[1];   // int64 narrowed to int32 by harness (validated)
    float* out = (float*)d_out;

    char* ws = (char*)d_ws;
    unsigned* part = (unsigned*)ws;                                  // C*NPART*NB*4 = 5.5 MB
    double* loss = (double*)(ws + (size_t)C * NPART * NB * 4);       // C*8
    unsigned long long* g = (unsigned long long*)(loss + C);         // C*8

    hist_kernel<<<dim3(CHUNKS, B * C), dim3(256), 0, stream>>>(
        (const float4*)pred, (const int4*)tgt, part, NB, (float)NB);
    class_kernel<<<dim3(C), dim3(NB), 0, stream>>>(part, loss, g);
    finalize_kernel<<<1, 64, 0, stream>>>(loss, g, out);
}

// Round 13
// 45.101 us; speedup vs baseline: 1.3251x; 1.0264x over previous
//
#include <hip/hip_runtime.h>
#include <stdint.h>

static constexpr int B = 8, C = 21, H = 512, W = 512;
static constexpr int HW = H * W;            // 262144
static constexpr int N = B * HW;            // 2097152 pixels
static constexpr int CHUNKS = 8;            // best measured geometry (r4/r12)
static constexpr int PPC = HW / CHUNKS;     // 32768 pixels per hist block (2^15: u16-pack safe)
static constexpr int ITER = PPC / 4 / 256;  // 32 float4 iters per thread
static constexpr int NPART = B * CHUNKS;    // 64 partials per class
static constexpr int NB = 1024;             // quantization bound 0.5/NB = 4.9e-4 << 1.77e-2

// ---------------------------------------------------------------------------
// Pass 1: LDS-privatized per-(class,bucket) histogram. EXACT round-4/12 body
// (validated). 1344 blocks x 256 thr; packed u32 (count lo16, gt hi16);
// flush = plain coalesced stores; zero global atomics. Block (0,0) zeroes the
// done counter (stream-ordered before pass 2; re-zeroed on every graph replay).
// ---------------------------------------------------------------------------
__global__ __launch_bounds__(256) void hist_kernel(const float4* __restrict__ pred,
                                                   const int4* __restrict__ lab4,
                                                   unsigned* __restrict__ part,
                                                   unsigned* __restrict__ done,
                                                   int nb, float nbf) {
    int chunk = blockIdx.x;               // 0..CHUNKS-1
    int bc = blockIdx.y;                  // b*C + c
    int b = bc / C, c = bc % C;
    int tid = threadIdx.x;

    if (chunk == 0 && bc == 0 && tid == 0) done[0] = 0u;

    __shared__ unsigned hcnt[NB];
    for (int j = tid; j < nb; j += 256) hcnt[j] = 0;
    __syncthreads();

    const float4* pp = pred + ((size_t)bc * HW + (size_t)chunk * PPC) / 4;
    const int4* lp = lab4 + ((size_t)b * HW + (size_t)chunk * PPC) / 4;
#pragma unroll 4
    for (int i = 0; i < ITER; ++i) {
        int idx = i * 256 + tid;
        float4 p = pp[idx];
        int4 lv = lp[idx];
        float pe[4] = {p.x, p.y, p.z, p.w};
        int le[4] = {lv.x, lv.y, lv.z, lv.w};
#pragma unroll
        for (int j = 0; j < 4; ++j) {
            unsigned ismatch = (le[j] == c) ? 1u : 0u;
            float e = fabsf((float)ismatch - pe[j]);
            int q = (int)(e * nbf);
            q = q > nb - 1 ? nb - 1 : (q < 0 ? 0 : q);
            atomicAdd(&hcnt[q], 1u | (ismatch << 16));
        }
    }
    __syncthreads();

    unsigned* dst = part + ((size_t)c * NPART + (size_t)(b * CHUNKS + chunk)) * NB;
    for (int j = tid; j < nb; j += 256) dst[j] = hcnt[j];   // coalesced
}

// ---------------------------------------------------------------------------
// Pass 2: one block per class, 1024 threads = one thread per bucket
// (q = NB-1-tid: tid order == descending error). Fold: each thread reads its
// bucket's 64 partials (wave-coalesced, slab L2/L3-resident). Prefix: the
// VALIDATED two-level form (r12; Hillis-Steele was the r8-r10 poison):
// group-of-4 sums -> serial thread-0 exclusive prefix over 256 groups ->
// <=3-term intra-group completion. Telescope per thread:
// e_rep*(J(k2,cg2)-J(k1,cg1)), J(k,cg)=1-(G-cg)/(G+k-cg).
// Finalize fused via round-4's EMPIRICALLY-PASSING last-block done-counter
// pattern (r8-10 failures fully attributed to H-S, which is gone).
// ---------------------------------------------------------------------------
__global__ __launch_bounds__(1024) void class_kernel(const unsigned* __restrict__ part,
                                                     double* __restrict__ loss_out,
                                                     unsigned long long* __restrict__ g_out,
                                                     unsigned* __restrict__ done,
                                                     float* __restrict__ out) {
    int c = blockIdx.x;
    int tid = threadIdx.x;
    int q = NB - 1 - tid;

    const unsigned* basep = part + (size_t)c * NPART * NB + q;
    unsigned n = 0, g = 0;
#pragma unroll 8
    for (int p = 0; p < NPART; ++p) {
        unsigned v = basep[(size_t)p * NB];
        n += v & 0xffffu;
        g += v >> 16;
    }

    __shared__ unsigned sn[NB], sg[NB];
    sn[tid] = n; sg[tid] = g;
    __syncthreads();

    // level 1: group-of-4 sums (threads 0..255)
    __shared__ unsigned gn[256], gg[256];
    if (tid < 256) {
        unsigned a = 0, b2 = 0;
#pragma unroll
        for (int i = 0; i < 4; ++i) { a += sn[4 * tid + i]; b2 += sg[4 * tid + i]; }
        gn[tid] = a; gg[tid] = b2;
    }
    __syncthreads();

    // level 2: serial exclusive prefix over 256 groups (validated r4/5/6/12)
    __shared__ unsigned exn[257], exg[257];
    if (tid == 0) {
        unsigned an = 0, ag = 0;
        for (int i = 0; i < 256; ++i) { exn[i] = an; exg[i] = ag; an += gn[i]; ag += gg[i]; }
        exn[256] = an; exg[256] = ag;
    }
    __syncthreads();

    unsigned G = exg[256];

    // per-thread exclusive prefix: group base + <=3 intra-group predecessors
    unsigned k1u = exn[tid >> 2], cg1u = exg[tid >> 2];
    for (int i = (tid & ~3); i < tid; ++i) { k1u += sn[i]; cg1u += sg[i]; }

    double acc = 0.0;
    if (G > 0 && n > 0) {
        double Gd = (double)G;
        double k1 = (double)k1u, cg1 = (double)cg1u;
        double k2 = k1 + (double)n, cg2 = cg1 + (double)g;
        double jprev = 1.0 - (Gd - cg1) / (Gd + k1 - cg1);
        double jnew  = 1.0 - (Gd - cg2) / (Gd + k2 - cg2);
        acc = (((double)q + 0.5) / (double)NB) * (jnew - jprev);
    }

    __shared__ double red[NB];
    red[tid] = acc;
    __syncthreads();
    for (int s = NB / 2; s > 0; s >>= 1) {
        if (tid < s) red[tid] += red[tid + s];
        __syncthreads();
    }
    if (tid == 0) {
        loss_out[c] = red[0];
        g_out[c] = G;
        __threadfence();                       // publish before signaling (r4 pattern)
        unsigned old = atomicAdd(done, 1u);    // device-scope
        if (old == C - 1) {                    // last class block finalizes
            __threadfence();
            double s = 0.0; int np = 0;
            for (int i = 0; i < C; ++i) {
                unsigned long long gi =
                    __hip_atomic_load(&g_out[i], __ATOMIC_RELAXED, __HIP_MEMORY_SCOPE_AGENT);
                double li =
                    __hip_atomic_load(&loss_out[i], __ATOMIC_RELAXED, __HIP_MEMORY_SCOPE_AGENT);
                if (gi > 0) { s += li; ++np; }
            }
            out[0] = (float)(s / (double)(np > 0 ? np : 1));
        }
    }
}

extern "C" void kernel_launch(void* const* d_in, const int* in_sizes, int n_in,
                              void* d_out, int out_size, void* d_ws, size_t ws_size,
                              hipStream_t stream) {
    const float* pred = (const float*)d_in[0];
    const int* tgt = (const int*)d_in[1];   // int64 narrowed to int32 by harness (validated)
    float* out = (float*)d_out;

    char* ws = (char*)d_ws;
    unsigned* part = (unsigned*)ws;                                  // C*NPART*NB*4 = 5.5 MB
    double* loss = (double*)(ws + (size_t)C * NPART * NB * 4);       // C*8
    unsigned long long* g = (unsigned long long*)(loss + C);         // C*8
    unsigned* done = (unsigned*)(g + C);                             // 4

    hist_kernel<<<dim3(CHUNKS, B * C), dim3(256), 0, stream>>>(
        (const float4*)pred, (const int4*)tgt, part, done, NB, (float)NB);
    class_kernel<<<dim3(C), dim3(NB), 0, stream>>>(part, loss, g, done, out);
}